// Round 8
// baseline (153.457 us; speedup 1.0000x reference)
//
#include <hip/hip_runtime.h>

constexpr int NB = 32;
constexpr int NPAIR = NB * NB;          // 1024 pair bins
constexpr int HSIZE = NPAIR + NB;       // 1056 bins (pairs + diag counts)
constexpr int NCPY = 4;                 // interleaved copies: addr = bin*4 + (lane&3)
constexpr int LWORDS = HSIZE * NCPY;    // 4224 words = 16.9 KB -> full occupancy
constexpr int DD = 96, HH = 96, WW = 96;
constexpr int SD = HH * WW;             // 9216
constexpr int SH = WW;                  // 96
constexpr int NVOX = 2 * DD * HH * WW;  // 1769472
constexpr int NCH = NVOX / 4;           // 442368 chunks of 4 voxels
constexpr int CW = WW / 4;              // 24 chunks per row
constexpr int NBLK = NCH / 256;         // 1728: exactly 1 chunk per thread
constexpr int NPART = 32;               // global partial histograms
constexpr int WSWORDS = NPART * HSIZE;  // 33792 partial words; counter at [WSWORDS]

__global__ void zero_kernel(unsigned int* ws) {
    int t = blockIdx.x * blockDim.x + threadIdx.x;   // 33 blocks x 256 = 8448 uint4
    ((uint4*)ws)[t] = make_uint4(0u, 0u, 0u, 0u);
    if (t == 0) ws[WSWORDS] = 0u;                    // completion counter
}

__global__ __launch_bounds__(256) void adj_kernel(const int* __restrict__ tgt,
                                                  unsigned int* __restrict__ ws,
                                                  float* __restrict__ out) {
    __shared__ unsigned int hist[LWORDS];
    __shared__ bool is_last;
    uint4* h4 = (uint4*)hist;
    for (int k = threadIdx.x; k < LWORDS / 4; k += 256)
        h4[k] = make_uint4(0u, 0u, 0u, 0u);
    __syncthreads();

    const int c  = blockIdx.x * 256 + threadIdx.x;   // grid sized exactly
    const int cw = c % CW;
    const int r  = c / CW;
    const int h  = r % HH;
    const int d  = (r / HH) % DD;    // batch boundary handled by dp guard
    const int v0 = c * 4;
    const unsigned int cp = threadIdx.x & (NCPY - 1);   // lane's private copy

    const bool hpv = (h + 1 < HH), hmv = (h > 0), dpv = (d + 1 < DD);
    const bool vL = (cw > 0), vR = (cw < CW - 1);

    int4 Cc = *(const int4*)(tgt + v0);
    int ci[4] = {Cc.x, Cc.y, Cc.z, Cc.w};
    int cR = vR ? tgt[v0 + 4] : 0;

    // neighbor rows for the 13 lexicographically-positive offsets:
    // (0,+1,*), (+1,-1,*), (+1,0,*), (+1,+1,*); plus (0,0,+1) in-row
    bool rowv[4];
    rowv[0] = hpv; rowv[1] = dpv && hmv; rowv[2] = dpv; rowv[3] = dpv && hpv;
    const int roff[4] = {SH, SD - SH, SD, SD + SH};
    int a[4][6];
#pragma unroll
    for (int q = 0; q < 4; q++) {
        if (rowv[q]) {
            const int* p = tgt + v0 + roff[q];
            int4 m = *(const int4*)p;
            a[q][1] = m.x; a[q][2] = m.y; a[q][3] = m.z; a[q][4] = m.w;
            a[q][0] = vL ? p[-1] : 0;
            a[q][5] = vR ? p[4]  : 0;
        }
    }

#pragma unroll
    for (int e = 0; e < 4; e++) {
        // bin (i,j) at (i*32+j)*4 + cp ; diag bin i at (1024+i)*4 + cp
        const unsigned int ib4 = (((unsigned int)ci[e]) << 7) + cp;  // i*32*4 + cp
        atomicAdd(&hist[((NPAIR + ci[e]) << 2) + cp], 1u);           // center diag
        if (e < 3)       atomicAdd(&hist[ib4 + (ci[e + 1] << 2)], 1u);  // (0,0,+1)
        else if (vR)     atomicAdd(&hist[ib4 + (cR << 2)], 1u);
#pragma unroll
        for (int q = 0; q < 4; q++) {
            if (rowv[q]) {
                if (e > 0 || vL) atomicAdd(&hist[ib4 + (a[q][e] << 2)], 1u);
                atomicAdd(&hist[ib4 + (a[q][e + 1] << 2)], 1u);
                if (e < 3 || vR) atomicAdd(&hist[ib4 + (a[q][e + 2] << 2)], 1u);
            }
        }
    }
    __syncthreads();

    // flush: one contiguous uint4 per bin, sum 4 copies, atomic to global partial
    unsigned int* part = ws + (size_t)(blockIdx.x & (NPART - 1)) * HSIZE;
    for (int k = threadIdx.x; k < HSIZE; k += 256) {
        uint4 u = ((const uint4*)hist)[k];
        unsigned int s = u.x + u.y + u.z + u.w;
        if (s) atomicAdd(&part[k], s);
    }

    // completion-counter fused finalize (threadFenceReduction pattern)
    __threadfence();
    __syncthreads();
    if (threadIdx.x == 0) {
        unsigned int old = atomicAdd(&ws[WSWORDS], 1u);
        is_last = (old == (unsigned int)(NBLK - 1));
    }
    __syncthreads();
    if (!is_last) return;

    __threadfence();
    volatile const unsigned int* vws = ws;
    for (int k = threadIdx.x; k < HSIZE; k += 256) {
        unsigned int acc = 0;
#pragma unroll 8
        for (int p = 0; p < NPART; ++p) acc += vws[p * HSIZE + k];
        hist[k] = acc;                 // reuse LDS: sums s[0..1055]
    }
    __syncthreads();
    for (int k = threadIdx.x; k < NPAIR; k += 256) {
        int i = k >> 5, j = k & 31;
        unsigned int v = hist[k] + hist[(j << 5) | i];
        if (i == j) v += hist[NPAIR + i];
        out[k] = (float)v;
    }
}

extern "C" void kernel_launch(void* const* d_in, const int* in_sizes, int n_in,
                              void* d_out, int out_size, void* d_ws, size_t ws_size,
                              hipStream_t stream) {
    const int* tgt = (const int*)d_in[0];
    float* out = (float*)d_out;
    unsigned int* ws = (unsigned int*)d_ws;

    zero_kernel<<<WSWORDS / 4 / 256, 256, 0, stream>>>(ws);   // 33 blocks
    adj_kernel<<<NBLK, 256, 0, stream>>>(tgt, ws, out);
}

// Round 9
// 24.208 us; speedup vs baseline: 6.3390x; 6.3390x over previous
//
#include <hip/hip_runtime.h>

constexpr int NB = 32;
constexpr int NPAIR = NB * NB;          // 1024 pair bins
constexpr int HSIZE = NPAIR + NB;       // 1056 bins (pairs + diag counts)
constexpr int NCPY = 4;                 // interleaved copies: addr = bin*4 + (lane&3)
constexpr int LWORDS = HSIZE * NCPY;    // 4224 words = 16.9 KB -> full occupancy
constexpr int DD = 96, HH = 96, WW = 96;
constexpr int SD = HH * WW;             // 9216
constexpr int SH = WW;                  // 96
constexpr int NVOX = 2 * DD * HH * WW;  // 1769472
constexpr int NCH = NVOX / 4;           // 442368 chunks of 4 voxels
constexpr int CW = WW / 4;              // 24 chunks per row
constexpr int NBLK = NCH / 256;         // 1728: exactly 1 chunk per thread
constexpr int NPART = 16;               // global partial histograms
constexpr int WSWORDS = NPART * HSIZE;  // 16896 words

__global__ void zero_kernel(unsigned int* ws) {
    int t = blockIdx.x * blockDim.x + threadIdx.x;   // 17 blocks x 256
    if (t < WSWORDS / 4) ((uint4*)ws)[t] = make_uint4(0u, 0u, 0u, 0u);
}

__global__ __launch_bounds__(256) void adj_kernel(const int* __restrict__ tgt,
                                                  unsigned int* __restrict__ ws) {
    __shared__ unsigned int hist[LWORDS];
    uint4* h4 = (uint4*)hist;
    for (int k = threadIdx.x; k < LWORDS / 4; k += 256)
        h4[k] = make_uint4(0u, 0u, 0u, 0u);
    __syncthreads();

    const int c  = blockIdx.x * 256 + threadIdx.x;   // grid sized exactly
    const int cw = c % CW;
    const int r  = c / CW;
    const int h  = r % HH;
    const int d  = (r / HH) % DD;    // batch boundary handled by dp guard
    const int v0 = c * 4;
    const unsigned int cp = threadIdx.x & (NCPY - 1);   // lane's private copy

    const bool hpv = (h + 1 < HH), hmv = (h > 0), dpv = (d + 1 < DD);
    const bool vL = (cw > 0), vR = (cw < CW - 1);

    int4 Cc = *(const int4*)(tgt + v0);
    int ci[4] = {Cc.x, Cc.y, Cc.z, Cc.w};
    int cR = vR ? tgt[v0 + 4] : 0;

    // neighbor rows for the 13 lexicographically-positive offsets:
    // (0,+1,*), (+1,-1,*), (+1,0,*), (+1,+1,*); plus (0,0,+1) in-row
    bool rowv[4];
    rowv[0] = hpv; rowv[1] = dpv && hmv; rowv[2] = dpv; rowv[3] = dpv && hpv;
    const int roff[4] = {SH, SD - SH, SD, SD + SH};
    int a[4][6];
#pragma unroll
    for (int q = 0; q < 4; q++) {
        if (rowv[q]) {
            const int* p = tgt + v0 + roff[q];
            int4 m = *(const int4*)p;
            a[q][1] = m.x; a[q][2] = m.y; a[q][3] = m.z; a[q][4] = m.w;
            a[q][0] = vL ? p[-1] : 0;
            a[q][5] = vR ? p[4]  : 0;
        }
    }

#pragma unroll
    for (int e = 0; e < 4; e++) {
        // bin (i,j) at (i*32+j)*4 + cp ; diag bin i at (1024+i)*4 + cp
        const unsigned int ib4 = (((unsigned int)ci[e]) << 7) + cp;  // i*32*4 + cp
        atomicAdd(&hist[((NPAIR + ci[e]) << 2) + cp], 1u);           // center diag
        if (e < 3)       atomicAdd(&hist[ib4 + (ci[e + 1] << 2)], 1u);  // (0,0,+1)
        else if (vR)     atomicAdd(&hist[ib4 + (cR << 2)], 1u);
#pragma unroll
        for (int q = 0; q < 4; q++) {
            if (rowv[q]) {
                if (e > 0 || vL) atomicAdd(&hist[ib4 + (a[q][e] << 2)], 1u);
                atomicAdd(&hist[ib4 + (a[q][e + 1] << 2)], 1u);
                if (e < 3 || vR) atomicAdd(&hist[ib4 + (a[q][e + 2] << 2)], 1u);
            }
        }
    }
    __syncthreads();

    // flush: one contiguous uint4 per bin, sum 4 copies, atomic to global partial
    unsigned int* part = ws + (size_t)(blockIdx.x & (NPART - 1)) * HSIZE;
    for (int k = threadIdx.x; k < HSIZE; k += 256) {
        uint4 u = ((const uint4*)hist)[k];
        unsigned int s = u.x + u.y + u.z + u.w;
        if (s) atomicAdd(&part[k], s);
    }
}

// single block, 1024 threads: coalesced sum of 16 partials, then LDS symmetrize
__global__ __launch_bounds__(1024) void final_kernel(const unsigned int* __restrict__ ws,
                                                     float* __restrict__ out) {
    __shared__ unsigned int s[NPAIR];
    __shared__ unsigned int nn[NB];
    const int k = threadIdx.x;
    unsigned int acc = 0;
#pragma unroll
    for (int p = 0; p < NPART; ++p) acc += ws[p * HSIZE + k];
    s[k] = acc;
    if (k < NB) {
        unsigned int a2 = 0;
#pragma unroll
        for (int p = 0; p < NPART; ++p) a2 += ws[p * HSIZE + NPAIR + k];
        nn[k] = a2;
    }
    __syncthreads();
    const int i = k >> 5, j = k & 31;
    unsigned int v = s[k] + s[(j << 5) | i];
    if (i == j) v += nn[i];
    out[k] = (float)v;
}

extern "C" void kernel_launch(void* const* d_in, const int* in_sizes, int n_in,
                              void* d_out, int out_size, void* d_ws, size_t ws_size,
                              hipStream_t stream) {
    const int* tgt = (const int*)d_in[0];
    float* out = (float*)d_out;
    unsigned int* ws = (unsigned int*)d_ws;

    zero_kernel<<<(WSWORDS / 4 + 255) / 256, 256, 0, stream>>>(ws);   // 17 blocks
    adj_kernel<<<NBLK, 256, 0, stream>>>(tgt, ws);
    final_kernel<<<1, 1024, 0, stream>>>(ws, out);
}

// Round 10
// 23.724 us; speedup vs baseline: 6.4683x; 1.0204x over previous
//
#include <hip/hip_runtime.h>

constexpr int NB = 32;
constexpr int NPAIR = NB * NB;          // 1024 pair bins
constexpr int HSIZE = NPAIR + NB;       // 1056 bins (pairs + diag counts)
constexpr int NCPY = 4;                 // interleaved copies: addr = bin*4 + (lane&3)
constexpr int LWORDS = HSIZE * NCPY;    // 4224 words = 16.9 KB -> full occupancy
constexpr int DD = 96, HH = 96, WW = 96;
constexpr int SD = HH * WW;             // 9216
constexpr int SH = WW;                  // 96
constexpr int NVOX = 2 * DD * HH * WW;  // 1769472
constexpr int NCH = NVOX / 4;           // 442368 chunks of 4 voxels
constexpr int CW = WW / 4;              // 24 chunks per row
constexpr int NBLK = NCH / 256;         // 1728: exactly 1 chunk per thread
constexpr int NPART = 32;               // global partial histograms (measured optimum)

__global__ void zero_kernel(unsigned int* ws, int n) {
    int t = blockIdx.x * blockDim.x + threadIdx.x;
    if (t < n) ws[t] = 0u;
}

__global__ __launch_bounds__(256) void adj_kernel(const int* __restrict__ tgt,
                                                  unsigned int* __restrict__ ws) {
    __shared__ unsigned int hist[LWORDS];
    uint4* h4 = (uint4*)hist;
    for (int k = threadIdx.x; k < LWORDS / 4; k += 256)
        h4[k] = make_uint4(0u, 0u, 0u, 0u);
    __syncthreads();

    const int c  = blockIdx.x * 256 + threadIdx.x;   // grid sized exactly
    const int cw = c % CW;
    const int r  = c / CW;
    const int h  = r % HH;
    const int d  = (r / HH) % DD;    // batch boundary handled by dp guard
    const int v0 = c * 4;
    const unsigned int cp = threadIdx.x & (NCPY - 1);   // lane's private copy

    const bool hpv = (h + 1 < HH), hmv = (h > 0), dpv = (d + 1 < DD);
    const bool vL = (cw > 0), vR = (cw < CW - 1);

    int4 Cc = *(const int4*)(tgt + v0);
    int ci[4] = {Cc.x, Cc.y, Cc.z, Cc.w};
    int cR = vR ? tgt[v0 + 4] : 0;

    // neighbor rows for the 13 lexicographically-positive offsets:
    // (0,+1,*), (+1,-1,*), (+1,0,*), (+1,+1,*); plus (0,0,+1) in-row
    bool rowv[4];
    rowv[0] = hpv; rowv[1] = dpv && hmv; rowv[2] = dpv; rowv[3] = dpv && hpv;
    const int roff[4] = {SH, SD - SH, SD, SD + SH};
    int a[4][6];
#pragma unroll
    for (int q = 0; q < 4; q++) {
        if (rowv[q]) {
            const int* p = tgt + v0 + roff[q];
            int4 m = *(const int4*)p;
            a[q][1] = m.x; a[q][2] = m.y; a[q][3] = m.z; a[q][4] = m.w;
            a[q][0] = vL ? p[-1] : 0;
            a[q][5] = vR ? p[4]  : 0;
        }
    }

#pragma unroll
    for (int e = 0; e < 4; e++) {
        // bin (i,j) at (i*32+j)*4 + cp ; diag bin i at (1024+i)*4 + cp
        const unsigned int ib4 = (((unsigned int)ci[e]) << 7) + cp;  // i*32*4 + cp
        atomicAdd(&hist[((NPAIR + ci[e]) << 2) + cp], 1u);           // center diag
        if (e < 3)       atomicAdd(&hist[ib4 + (ci[e + 1] << 2)], 1u);  // (0,0,+1)
        else if (vR)     atomicAdd(&hist[ib4 + (cR << 2)], 1u);
#pragma unroll
        for (int q = 0; q < 4; q++) {
            if (rowv[q]) {
                if (e > 0 || vL) atomicAdd(&hist[ib4 + (a[q][e] << 2)], 1u);
                atomicAdd(&hist[ib4 + (a[q][e + 1] << 2)], 1u);
                if (e < 3 || vR) atomicAdd(&hist[ib4 + (a[q][e + 2] << 2)], 1u);
            }
        }
    }
    __syncthreads();

    // flush: one contiguous uint4 per bin, sum 4 copies, atomic to global partial
    unsigned int* part = ws + (size_t)(blockIdx.x & (NPART - 1)) * HSIZE;
    for (int k = threadIdx.x; k < HSIZE; k += 256) {
        uint4 u = ((const uint4*)hist)[k];
        unsigned int s = u.x + u.y + u.z + u.w;
        if (s) atomicAdd(&part[k], s);
    }
}

// single block, 1024 threads: coalesced sum of 32 partials, then LDS symmetrize
__global__ __launch_bounds__(1024) void final_kernel(const unsigned int* __restrict__ ws,
                                                     float* __restrict__ out) {
    __shared__ unsigned int s[NPAIR];
    __shared__ unsigned int nn[NB];
    const int k = threadIdx.x;
    unsigned int acc = 0;
#pragma unroll 8
    for (int p = 0; p < NPART; ++p) acc += ws[p * HSIZE + k];
    s[k] = acc;
    if (k < NB) {
        unsigned int a2 = 0;
#pragma unroll 8
        for (int p = 0; p < NPART; ++p) a2 += ws[p * HSIZE + NPAIR + k];
        nn[k] = a2;
    }
    __syncthreads();
    const int i = k >> 5, j = k & 31;
    unsigned int v = s[k] + s[(j << 5) | i];
    if (i == j) v += nn[i];
    out[k] = (float)v;
}

extern "C" void kernel_launch(void* const* d_in, const int* in_sizes, int n_in,
                              void* d_out, int out_size, void* d_ws, size_t ws_size,
                              hipStream_t stream) {
    const int* tgt = (const int*)d_in[0];
    float* out = (float*)d_out;
    unsigned int* ws = (unsigned int*)d_ws;

    const int zn = NPART * HSIZE;   // 33792 words
    zero_kernel<<<(zn + 255) / 256, 256, 0, stream>>>(ws, zn);
    adj_kernel<<<NBLK, 256, 0, stream>>>(tgt, ws);
    final_kernel<<<1, 1024, 0, stream>>>(ws, out);
}